// Round 5
// baseline (453.406 us; speedup 1.0000x reference)
//
#include <hip/hip_runtime.h>

// Cross-stitch: out_a = w[c][0][0]*x_a + w[c][0][1]*x_b
//               out_b = w[c][1][0]*x_a + w[c][1][1]*x_b
// Shapes: x_a, x_b : [N=32, C=256, H=64, W=64] fp32, w : [C,2,2] fp32.
// d_out = out_a (N*C*H*W floats) followed by out_b (N*C*H*W floats).
//
// Memory-bound: 536.9 MB irreducible traffic -> ~85 us floor at 6.3 TB/s.
// Round-2 evidence: kernel dispatch absent from top-5 (all harness fills at
// ~164 us) -> kernel itself is already < 163 us; bench dur_us carries a
// ~300 us fixed harness offset (poison fill + input restore).
//
// v3 changes vs v2b:
//  * PLAIN (cached) loads for xa/xb: inputs (268 MB) are restored by the
//    harness immediately before launch -> mostly L3-resident (256 MiB).
//    v2b's nontemporal loads threw those hits away. Keep nt on STORES only
//    (no in-kernel reuse; avoids evicting input lines from L2/L3).
//  * Plane-PAIR per block-iteration: 16 x 16B loads in flight per thread
//    before any dependent use (2x MLP of v2b). ~64 data VGPRs, still
//    >= 5 waves/SIMD.
//
// (Rounds 3-4: infra failures — container never came up; kernel unchanged.)

typedef float f32x4 __attribute__((ext_vector_type(4)));

#define PLANE_V4 1024        // f32x4 per (n,c) plane
#define CMASK    255         // C-1, C=256

__global__ __launch_bounds__(256) void cross_stitch_kernel(
    const f32x4* __restrict__ xa,
    const f32x4* __restrict__ xb,
    const float* __restrict__ w,   // [C,2,2] flat
    f32x4* __restrict__ oa,
    f32x4* __restrict__ ob,
    int n_pairs)                   // n_planes / 2
{
    const int tid = threadIdx.x;

    for (int pair = blockIdx.x; pair < n_pairs; pair += gridDim.x) {
        const int p0 = pair * 2;
        const int c0 = p0 & CMASK;            // block-uniform -> SGPR
        const int c1 = (p0 + 1) & CMASK;

        const float w00_0 = w[c0 * 4 + 0], w01_0 = w[c0 * 4 + 1];
        const float w10_0 = w[c0 * 4 + 2], w11_0 = w[c0 * 4 + 3];
        const float w00_1 = w[c1 * 4 + 0], w01_1 = w[c1 * 4 + 1];
        const float w10_1 = w[c1 * 4 + 2], w11_1 = w[c1 * 4 + 3];

        const int base0 = p0 * PLANE_V4 + tid;
        const int base1 = base0 + PLANE_V4;

        // Issue all 16 loads before any dependent use.
        f32x4 a[8], b[8];
#pragma unroll
        for (int k = 0; k < 4; ++k) a[k]     = xa[base0 + k * 256];
#pragma unroll
        for (int k = 0; k < 4; ++k) a[4 + k] = xa[base1 + k * 256];
#pragma unroll
        for (int k = 0; k < 4; ++k) b[k]     = xb[base0 + k * 256];
#pragma unroll
        for (int k = 0; k < 4; ++k) b[4 + k] = xb[base1 + k * 256];

#pragma unroll
        for (int k = 0; k < 4; ++k) {
            f32x4 ra, rb;
#pragma unroll
            for (int j = 0; j < 4; ++j) {
                ra[j] = fmaf(w00_0, a[k][j], w01_0 * b[k][j]);
                rb[j] = fmaf(w10_0, a[k][j], w11_0 * b[k][j]);
            }
            __builtin_nontemporal_store(ra, &oa[base0 + k * 256]);
            __builtin_nontemporal_store(rb, &ob[base0 + k * 256]);
        }
#pragma unroll
        for (int k = 0; k < 4; ++k) {
            f32x4 ra, rb;
#pragma unroll
            for (int j = 0; j < 4; ++j) {
                ra[j] = fmaf(w00_1, a[4 + k][j], w01_1 * b[4 + k][j]);
                rb[j] = fmaf(w10_1, a[4 + k][j], w11_1 * b[4 + k][j]);
            }
            __builtin_nontemporal_store(ra, &oa[base1 + k * 256]);
            __builtin_nontemporal_store(rb, &ob[base1 + k * 256]);
        }
    }
}

extern "C" void kernel_launch(void* const* d_in, const int* in_sizes, int n_in,
                              void* d_out, int out_size, void* d_ws, size_t ws_size,
                              hipStream_t stream) {
    const f32x4* xa = (const f32x4*)d_in[0];
    const f32x4* xb = (const f32x4*)d_in[1];
    const float* w  = (const float*)d_in[2];

    const int n_elem   = in_sizes[0];            // 32*256*64*64 = 33,554,432
    const int n_vec4   = n_elem / 4;             // 8,388,608
    const int n_planes = n_vec4 / PLANE_V4;      // 8192 (n,c) planes
    const int n_pairs  = n_planes / 2;           // 4096

    f32x4* oa = (f32x4*)d_out;
    f32x4* ob = (f32x4*)d_out + n_vec4;

    const int block = 256;
    const int grid  = (n_pairs < 2048) ? n_pairs : 2048;  // 8 blocks/CU cap
    cross_stitch_kernel<<<grid, block, 0, stream>>>(xa, xb, w, oa, ob, n_pairs);
}